// Round 18
// baseline (148.316 us; speedup 1.0000x reference)
//
#include <hip/hip_runtime.h>
#include <hip/hip_cooperative_groups.h>

// AdaptiveSparsityAttention on MI355X (gfx950).
// f32 in/out, internal bf16 MFMA; mask logits in pure f32 via algebraic
// fusion:  a = x @ (0.5*(Wq[:,:256]+Wq[:,256:]) @ W1[:256]) + b1.
//
// R18: cooperative retry. R17's coop launch was REJECTED (out == 0 exactly):
//   48KB LDS -> 1 blk/CU under the runtime's 64KB/CU occupancy budget ->
//   512 > max co-resident. Fix: every phase <= 32KB LDS (qkv MF=1; scores
//   ct chunked 16), runtime occupancy query + return-code check, fallback
//   to 5 ordinary launches sharing the same __device__ phase bodies.

namespace cg = cooperative_groups;

typedef unsigned short u16t;
typedef __bf16 bf16x8 __attribute__((ext_vector_type(8)));
typedef float f32x4 __attribute__((ext_vector_type(4)));

#define B_SZ 2
#define S_SZ 1024
#define D_SZ 512
#define DH 256
#define HH 128

static __device__ __forceinline__ u16t f2b(float f) {
    unsigned int u = __builtin_bit_cast(unsigned int, f);
    u += 0x7FFFu + ((u >> 16) & 1u);
    return (u16t)(u >> 16);
}

static __device__ __forceinline__ f32x4 mfma16(bf16x8 a, bf16x8 b, f32x4 c) {
    return __builtin_amdgcn_mfma_f32_16x16x32_bf16(a, b, c, 0, 0, 0);
}

static __device__ __forceinline__ void gload16(const void* g, void* l) {
    __builtin_amdgcn_global_load_lds(
        (const __attribute__((address_space(1))) void*)g,
        (__attribute__((address_space(3))) void*)l, 16, 0, 0);
}

// ---------------------------- 2-phase double-buffered GEMM mainloop (swizzled)
template<int MF, int NF>
static __device__ __forceinline__ void gemm_db(
    const u16t* __restrict__ A, int lda, const u16t* __restrict__ B, int ldb,
    int K, int tid, u16t* Als, u16t* Bls, f32x4 acc[MF][NF])
{
    const int w = tid >> 6, lane = tid & 63;
    const int lr = lane & 15, kg = lane >> 4;
    const int srow = lane >> 3;
    const int scol = ((lane & 7) ^ srow) * 8;
    const int ABUF = MF * 4096;
    const int BBUF = NF * 1024;
    auto stage = [&](int bb, int k0) {
#pragma unroll
        for (int q = 0; q < MF * 2; ++q) {
            int ci = w * (MF * 2) + q;
            gload16(A + (size_t)(ci * 8 + srow) * lda + k0 + scol,
                    Als + bb * ABUF + ci * 512);
        }
#pragma unroll
        for (int q = 0; q < NF / 2; ++q) {
            int cj = w * (NF / 2) + q;
            gload16(B + (size_t)(cj * 8 + srow) * ldb + k0 + scol,
                    Bls + bb * BBUF + cj * 512);
        }
    };
    stage(0, 0);
    __syncthreads();
    const int nt = K / 64;
    for (int t = 0; t < nt; ++t) {
        int cur = t & 1;
        if (t + 1 < nt) stage(cur ^ 1, (t + 1) * 64);
        const u16t* Ab = Als + cur * ABUF;
        const u16t* Bb = Bls + cur * BBUF;
#pragma unroll
        for (int kk = 0; kk < 2; ++kk) {
            bf16x8 af[MF], bfr[NF];
#pragma unroll
            for (int fi = 0; fi < MF; ++fi) {
                int r = w * (MF * 16) + fi * 16 + lr;
                af[fi] = *(const bf16x8*)(&Ab[r * 64 + (((kk * 4 + kg) ^ (r & 7)) << 3)]);
            }
#pragma unroll
            for (int fj = 0; fj < NF; ++fj) {
                int r = fj * 16 + lr;
                bfr[fj] = *(const bf16x8*)(&Bb[r * 64 + (((kk * 4 + kg) ^ (r & 7)) << 3)]);
            }
#pragma unroll
            for (int fi = 0; fi < MF; ++fi)
#pragma unroll
                for (int fj = 0; fj < NF; ++fj)
                    acc[fi][fj] = mfma16(af[fi], bfr[fj], acc[fi][fj]);
        }
        __syncthreads();
    }
}

// ============================ phase bodies (shared mega/wrapper) ============

// ---- P0: prep. 2560 vb.
static __device__ void ph_prep(int vb, int t, char* sm,
    const float* x, const float* Wq, const float* Wk, const float* Wv,
    const float* Wo, const float* W1,
    u16t* xb, u16t* WT, float* Beff)
{
    float* smf = (float*)sm;
    if (vb < 1024) {
        int idx = (vb * 256 + t) * 4;
        float4 v = *(const float4*)(x + idx);
        u16t* o = xb + idx;
        o[0] = f2b(v.x); o[1] = f2b(v.y); o[2] = f2b(v.z); o[3] = f2b(v.w);
    } else if (vb < 2048) {
        int t2 = vb - 1024;
        int z = t2 >> 8, rem = t2 & 255;
        int n0 = (rem & 15) * 32, k0 = (rem >> 4) * 32;
        const float* W = z == 0 ? Wq : z == 1 ? Wk : z == 2 ? Wv : Wo;
        u16t* WTz = WT + (size_t)z * D_SZ * D_SZ;
        float (*tile)[33] = (float(*)[33])smf;
        int r = t >> 3, c4 = (t & 7) * 4;
        float4 v = *(const float4*)(W + (size_t)(k0 + r) * D_SZ + n0 + c4);
        tile[r][c4] = v.x; tile[r][c4 + 1] = v.y; tile[r][c4 + 2] = v.z; tile[r][c4 + 3] = v.w;
        __syncthreads();
        u16t o[4];
        o[0] = f2b(tile[c4][r]); o[1] = f2b(tile[c4 + 1][r]);
        o[2] = f2b(tile[c4 + 2][r]); o[3] = f2b(tile[c4 + 3][r]);
        *(ushort4*)(WTz + (size_t)(n0 + r) * D_SZ + k0 + c4) = *(ushort4*)o;
    } else {
        int k = vb - 2048;
        float* wm0 = smf;
        float* wm1 = smf + 256;
        const float* wrq = Wq + (size_t)k * D_SZ;
        const float* wrk = Wk + (size_t)k * D_SZ;
        wm0[t & 255] = 0.5f * (wrq[t & 255] + wrq[(t & 255) + DH]);
        wm1[t & 255] = 0.5f * (wrk[t & 255] + wrk[(t & 255) + DH]);
        __syncthreads();
        int half = t >> 7, hcol = t & 127;
        const float* wm = half ? wm1 : wm0;
        const float* W1h = W1 + (half ? (size_t)DH * HH : 0);
        float s = 0.f;
        for (int d = 0; d < 256; ++d) s += wm[d] * W1h[(size_t)d * HH + hcol];
        Beff[(size_t)k * 256 + half * 128 + hcol] = s;
    }
}

// ---- P1: qkv (BM=64, MF=1, vb<768) + ac (vb in [768,1024)).
static __device__ void ph_qkvac(int vb, int t, char* sm,
    const u16t* xb, const u16t* WT, const float* x, const float* Beff,
    const float* b1,
    u16t* qb, u16t* kb, u16t* vT, float* a, float* cc)
{
    if (vb < 768) {
        u16t* Als = (u16t*)sm;               // 2 x 8KB
        u16t* Bls = (u16t*)(sm + 16384);     // 2 x 8KB  -> 32KB total
        int z = vb >> 8, rem = vb & 255;
        int m0 = (rem >> 3) * 64, n0 = (rem & 7) * 64;
        const u16t* A = xb + (size_t)m0 * D_SZ;
        const u16t* Bt = WT + (size_t)z * D_SZ * D_SZ + (size_t)n0 * D_SZ;
        f32x4 acc[1][4] = {};
        gemm_db<1, 4>(A, D_SZ, Bt, D_SZ, D_SZ, t, Als, Bls, acc);
        int w = t >> 6, lane = t & 63, lr = lane & 15, kg = lane >> 4;
        if (z < 2) {
            u16t (*vls)[68] = (u16t(*)[68])sm;   // 64x68 = 8704B
            float scale = z == 0 ? 0.0625f : 1.0f;
#pragma unroll
            for (int fj = 0; fj < 4; ++fj)
#pragma unroll
                for (int rr = 0; rr < 4; ++rr)
                    vls[w * 16 + kg * 4 + rr][fj * 16 + lr]
                        = f2b(acc[0][fj][rr] * scale);
            __syncthreads();
            u16t* dst = z == 0 ? qb : kb;
            int c8 = (t & 7) * 8, r0 = t >> 3;
#pragma unroll
            for (int p = 0; p < 2; ++p) {
                int r = r0 + p * 32;
                *(uint4*)(dst + (size_t)(m0 + r) * D_SZ + n0 + c8) = *(const uint4*)(&vls[r][c8]);
            }
        } else {
            u16t (*vls)[72] = (u16t(*)[72])sm;   // [d][s] 64x72 = 9216B
#pragma unroll
            for (int fj = 0; fj < 4; ++fj)
#pragma unroll
                for (int rr = 0; rr < 4; ++rr)
                    vls[fj * 16 + lr][w * 16 + kg * 4 + rr] = f2b(acc[0][fj][rr]);
            __syncthreads();
            int b = m0 >> 10, s0 = m0 & 1023;
            int cr = t >> 2, seg = t & 3;
            const u16t* srcp = &vls[cr][seg * 16];
            u16t* dstp = vT + (((size_t)(b * D_SZ + n0 + cr)) << 10) + s0 + seg * 16;
            *(uint4*)dstp = *(const uint4*)srcp;
            *(uint4*)(dstp + 8) = *(const uint4*)(srcp + 8);
        }
    } else {
        float (*xs)[68] = (float(*)[68])sm;            // 17408B
        float (*bsT)[68] = (float(*)[68])(sm + 17408); // 8704B
        int t2 = vb - 768;
        int r0 = (t2 & 31) * 64, n0 = (t2 >> 5) * 32;
        int ti = t >> 4, tj = t & 15;
        float acc[4][2] = {};
        for (int k0 = 0; k0 < 512; k0 += 64) {
            if (k0) __syncthreads();
#pragma unroll
            for (int p = 0; p < 4; ++p) {
                int idx = t + p * 256;
                int r = idx >> 4, c4 = (idx & 15) * 4;
                *(float4*)&xs[r][c4] = *(const float4*)(x + (size_t)(r0 + r) * D_SZ + k0 + c4);
            }
#pragma unroll
            for (int p = 0; p < 2; ++p) {
                int idx = t + p * 256;
                int k = idx >> 3, n4 = (idx & 7) * 4;
                float4 v = *(const float4*)(Beff + (size_t)(k0 + k) * 256 + n0 + n4);
                bsT[n4][k] = v.x; bsT[n4 + 1][k] = v.y; bsT[n4 + 2][k] = v.z; bsT[n4 + 3][k] = v.w;
            }
            __syncthreads();
#pragma unroll
            for (int kk = 0; kk < 16; ++kk) {
                float4 xv[4], bv[2];
#pragma unroll
                for (int ri = 0; ri < 4; ++ri) xv[ri] = *(const float4*)&xs[ti + 16 * ri][kk * 4];
#pragma unroll
                for (int rj = 0; rj < 2; ++rj) bv[rj] = *(const float4*)&bsT[tj + 16 * rj][kk * 4];
#pragma unroll
                for (int ri = 0; ri < 4; ++ri)
#pragma unroll
                    for (int rj = 0; rj < 2; ++rj)
                        acc[ri][rj] += xv[ri].x * bv[rj].x + xv[ri].y * bv[rj].y
                                     + xv[ri].z * bv[rj].z + xv[ri].w * bv[rj].w;
            }
        }
        bool isA = n0 < 128;
#pragma unroll
        for (int rj = 0; rj < 2; ++rj) {
            int col = n0 + tj + 16 * rj;
            float badd = isA ? b1[col] : 0.f;
#pragma unroll
            for (int ri = 0; ri < 4; ++ri) {
                int row = r0 + ti + 16 * ri;
                if (isA) a[(size_t)row * HH + col] = acc[ri][rj] + badd;
                else     cc[(size_t)row * HH + (col - 128)] = acc[ri][rj];
            }
        }
    }
}

// ---- P2: scores (BM=32, 1024 vb). LDS <= 29.7KB.
static __device__ void ph_scores(int vb, int t, char* sm,
    const u16t* qb, const u16t* kb, const float* a, const float* cc,
    const float* W2, const float* b2, u16t* P, float* lpart)
{
    float (*at)[132] = (float(*)[132])sm;                          // 16896B
    float (*ct)[132] = (float(*)[132])(sm + 16896);                // 16 rows, 8448B
    unsigned char (*msk)[64] = (unsigned char(*)[64])(sm + 26624); // 2048B persists
    float* w2s  = (float*)(sm + 28672);                            // 512B
    float* lsum = (float*)(sm + 29184);                            // 512B
    int jb = vb & 15, mt = (vb >> 4) & 31, b = vb >> 9;
    int m0 = mt * 32, j0 = jb * 64;
    if (t < 128) w2s[t] = W2[t];
    float fb2 = b2[0];
    int ti = t >> 4, tj = t & 15;
#pragma unroll
    for (int p = 0; p < 4; ++p) {
        int idx = t + p * 256;
        int r = idx >> 5, c4 = (idx & 31) * 4;
        *(float4*)&at[r][c4] = *(const float4*)(a + ((size_t)(b * S_SZ + m0 + r)) * HH + c4);
    }
    // ---- phase 1: mask tile (four j-chunks of 16) ----
#pragma unroll
    for (int jq = 0; jq < 4; ++jq) {
        __syncthreads();
#pragma unroll
        for (int p = 0; p < 2; ++p) {
            int idx = t + p * 256;
            int r = idx >> 5, c4 = (idx & 31) * 4;
            *(float4*)&ct[r][c4] =
                *(const float4*)(cc + ((size_t)(b * S_SZ + j0 + jq * 16 + r)) * HH + c4);
        }
        __syncthreads();
        float accm[2];
        accm[0] = fb2; accm[1] = fb2;
#pragma unroll 2
        for (int h4 = 0; h4 < 32; ++h4) {
            float4 wv = ((const float4*)w2s)[h4];
            float4 cv = *(const float4*)&ct[tj][h4 * 4];
#pragma unroll
            for (int ri = 0; ri < 2; ++ri) {
                float4 av = *(const float4*)&at[ti + 16 * ri][h4 * 4];
                accm[ri] += fmaxf(av.x + cv.x, 0.f) * wv.x;
                accm[ri] += fmaxf(av.y + cv.y, 0.f) * wv.y;
                accm[ri] += fmaxf(av.z + cv.z, 0.f) * wv.z;
                accm[ri] += fmaxf(av.w + cv.w, 0.f) * wv.w;
            }
        }
#pragma unroll
        for (int ri = 0; ri < 2; ++ri)
            msk[ti + 16 * ri][jq * 16 + tj] = accm[ri] > 0.f ? 1 : 0;
    }
    __syncthreads();   // at/ct readers done; GEMM bufs overlay
    // ---- phase 2: QK^T both heads (K=512 concat; qb pre-scaled 1/16) ----
    u16t* Als = (u16t*)sm;             // 2 x 4KB
    u16t* Bls = (u16t*)(sm + 8192);    // 2 x 8KB
    const u16t* A = qb + (size_t)(b * S_SZ + m0) * D_SZ;
    const u16t* B = kb + (size_t)(b * S_SZ + j0) * D_SZ;
    const int w = t >> 6, lane = t & 63, lr = lane & 15, kg = lane >> 4;
    const int srow = lane >> 3;
    const int scol = ((lane & 7) ^ srow) * 8;
    auto stage = [&](int bb, int k0) {
        gload16(A + (size_t)(w * 8 + srow) * D_SZ + k0 + scol, Als + bb * 2048 + w * 512);
#pragma unroll
        for (int q = 0; q < 2; ++q) {
            int cj = w * 2 + q;
            gload16(B + (size_t)(cj * 8 + srow) * D_SZ + k0 + scol, Bls + bb * 4096 + cj * 512);
        }
    };
    f32x4 acc0[2] = {}, acc1[2] = {};
    stage(0, 0);
    __syncthreads();
#pragma unroll
    for (int t8 = 0; t8 < 8; ++t8) {
        int cur = t8 & 1;
        if (t8 < 7) stage(cur ^ 1, (t8 + 1) * 64);
        const u16t* Ab = Als + cur * 2048;
        const u16t* Bb = Bls + cur * 4096;
#pragma unroll
        for (int kk = 0; kk < 2; ++kk) {
            int rb = w * 16 + lr;
            bf16x8 bfr = *(const bf16x8*)(&Bb[rb * 64 + (((kk * 4 + kg) ^ (rb & 7)) << 3)]);
            bf16x8 af[2];
#pragma unroll
            for (int fi = 0; fi < 2; ++fi) {
                int ra = fi * 16 + lr;
                af[fi] = *(const bf16x8*)(&Ab[ra * 64 + (((kk * 4 + kg) ^ (ra & 7)) << 3)]);
            }
            if (t8 < 4) {
#pragma unroll
                for (int fi = 0; fi < 2; ++fi) acc0[fi] = mfma16(af[fi], bfr, acc0[fi]);
            } else {
#pragma unroll
                for (int fi = 0; fi < 2; ++fi) acc1[fi] = mfma16(af[fi], bfr, acc1[fi]);
            }
        }
        __syncthreads();
    }
    // ---- phase 3: exp + mask + lpart + P store, per head ----
    u16t (*vls)[68] = (u16t(*)[68])sm;   // 4352B overlays
#pragma unroll
    for (int h = 0; h < 2; ++h) {
#pragma unroll
        for (int fi = 0; fi < 2; ++fi)
#pragma unroll
            for (int rr = 0; rr < 4; ++rr) {
                int il = fi * 16 + kg * 4 + rr;
                int jl = w * 16 + lr;
                float s = h ? acc1[fi][rr] : acc0[fi][rr];
                float e = msk[il][jl] ? __expf(s) : 0.f;
                if (h) acc1[fi][rr] = e; else acc0[fi][rr] = e;
            }
#pragma unroll
        for (int fi = 0; fi < 2; ++fi)
#pragma unroll
            for (int rr = 0; rr < 4; ++rr) {
                float rs = h ? acc1[fi][rr] : acc0[fi][rr];
                rs += __shfl_xor(rs, 1); rs += __shfl_xor(rs, 2);
                rs += __shfl_xor(rs, 4); rs += __shfl_xor(rs, 8);
                if (lr == 0) lsum[w * 32 + fi * 16 + kg * 4 + rr] = rs;
            }
        __syncthreads();
        if (t < 32) {
            float l = lsum[t] + lsum[32 + t] + lsum[64 + t] + lsum[96 + t];
            lpart[((size_t)(jb * 4 + b * 2 + h) << 10) + m0 + t] = l;
        }
#pragma unroll
        for (int fi = 0; fi < 2; ++fi)
#pragma unroll
            for (int rr = 0; rr < 4; ++rr)
                vls[fi * 16 + kg * 4 + rr][w * 16 + lr]
                    = f2b(h ? acc1[fi][rr] : acc0[fi][rr]);
        __syncthreads();
        int r = t >> 3, c8 = (t & 7) * 8;
        *(uint4*)(P + ((size_t)(b * 2 + h) << 20) + ((size_t)(m0 + r) << 10) + j0 + c8)
            = *(const uint4*)(&vls[r][c8]);
        __syncthreads();
    }
}

// ---- P3: pv (512 vb).
static __device__ void ph_pv(int vb, int t, char* sm,
    const u16t* P, const u16t* vT, const float* lpart, u16t* ao)
{
    u16t* Als = (u16t*)sm;               // 2 x 8KB
    u16t* Bls = (u16t*)(sm + 16384);     // 2 x 4KB
    float* invl = (float*)(sm + 24576);  // 256B
    int xw = vb & 7, yw = (vb >> 3) & 15, bh = vb >> 7;
    int b = bh >> 1, h = bh & 1;
    int m0 = yw * 64, n0 = xw * 32;
    if (t < 64) {
        float l = 0.f;
        for (int jb = 0; jb < 16; ++jb)
            l += lpart[((size_t)(jb * 4 + bh) << 10) + m0 + t];
        invl[t] = l > 0.f ? 1.0f / l : 0.f;
    }
    const u16t* A = P + ((size_t)bh << 20) + (size_t)m0 * S_SZ;
    const u16t* Bt = vT + ((size_t)(b * D_SZ + h * DH + n0)) * S_SZ;
    f32x4 acc[1][2] = {};
    gemm_db<1, 2>(A, S_SZ, Bt, S_SZ, S_SZ, t, Als, Bls, acc);
    int w = t >> 6, lane = t & 63, lr = lane & 15, kg = lane >> 4;
    u16t (*ols)[40] = (u16t(*)[40])sm;   // 5120B overlays
#pragma unroll
    for (int fj = 0; fj < 2; ++fj)
#pragma unroll
        for (int rr = 0; rr < 4; ++rr) {
            int rl = w * 16 + kg * 4 + rr;
            ols[rl][fj * 16 + lr] = f2b(acc[0][fj][rr] * invl[rl]);
        }
    __syncthreads();
    int r = t >> 2, c8 = (t & 3) * 8;
    *(uint4*)(ao + ((size_t)(b * S_SZ + m0 + r)) * D_SZ + h * DH + n0 + c8)
        = *(const uint4*)(&ols[r][c8]);
}

// ---- P4: out (512 vb).
static __device__ void ph_out(int vb, int t, char* sm,
    const u16t* ao, const u16t* WT, const float* bo, float* out)
{
    u16t* Als = (u16t*)sm;
    u16t* Bls = (u16t*)(sm + 16384);
    int m0 = (vb >> 4) * 64, n0 = (vb & 15) * 32;
    const u16t* A = ao + (size_t)m0 * D_SZ;
    const u16t* Bt = WT + (size_t)3 * D_SZ * D_SZ + (size_t)n0 * D_SZ;
    f32x4 acc[1][2] = {};
    gemm_db<1, 2>(A, D_SZ, Bt, D_SZ, D_SZ, t, Als, Bls, acc);
    int w = t >> 6, lane = t & 63, lr = lane & 15, kg = lane >> 4;
    float (*ols)[36] = (float(*)[36])sm;   // 9216B overlays
#pragma unroll
    for (int fj = 0; fj < 2; ++fj)
#pragma unroll
        for (int rr = 0; rr < 4; ++rr) {
            int rl = w * 16 + kg * 4 + rr;
            ols[rl][fj * 16 + lr] = acc[0][fj][rr] + bo[n0 + fj * 16 + lr];
        }
    __syncthreads();
    int r0 = t >> 3, c4 = (t & 7) * 4;
#pragma unroll
    for (int p = 0; p < 2; ++p) {
        int r = r0 + p * 32;
        *(float4*)(out + (size_t)(m0 + r) * D_SZ + n0 + c4) = *(const float4*)(&ols[r][c4]);
    }
}

// ============================ kernels ============================

__global__ __launch_bounds__(256, 2) void k_mega(
    const float* __restrict__ x,
    const float* __restrict__ Wq, const float* __restrict__ Wk,
    const float* __restrict__ Wv, const float* __restrict__ Wo,
    const float* __restrict__ bo, const float* __restrict__ W1,
    const float* __restrict__ b1, const float* __restrict__ W2,
    const float* __restrict__ b2,
    u16t* __restrict__ xb, u16t* __restrict__ WT, float* __restrict__ Beff,
    u16t* __restrict__ qb, u16t* __restrict__ kb, u16t* __restrict__ vT,
    float* __restrict__ a, float* __restrict__ cc,
    u16t* __restrict__ P, float* __restrict__ lpart,
    u16t* __restrict__ ao, float* __restrict__ out)
{
    __shared__ __align__(16) char sm[32768];
    cg::grid_group grid = cg::this_grid();
    const int G = gridDim.x;
    const int t = threadIdx.x;
    for (int vb = blockIdx.x; vb < 2560; vb += G) {
        ph_prep(vb, t, sm, x, Wq, Wk, Wv, Wo, W1, xb, WT, Beff);
        __syncthreads();
    }
    grid.sync();
    for (int vb = blockIdx.x; vb < 1024; vb += G) {
        ph_qkvac(vb, t, sm, xb, WT, x, Beff, b1, qb, kb, vT, a, cc);
        __syncthreads();
    }
    grid.sync();
    for (int vb = blockIdx.x; vb < 1024; vb += G) {
        ph_scores(vb, t, sm, qb, kb, a, cc, W2, b2, P, lpart);
        __syncthreads();
    }
    grid.sync();
    for (int vb = blockIdx.x; vb < 512; vb += G) {
        ph_pv(vb, t, sm, P, vT, lpart, ao);
        __syncthreads();
    }
    grid.sync();
    for (int vb = blockIdx.x; vb < 512; vb += G) {
        ph_out(vb, t, sm, ao, WT, bo, out);
        __syncthreads();
    }
}

__global__ __launch_bounds__(256) void kw_prep(
    const float* x, const float* Wq, const float* Wk, const float* Wv,
    const float* Wo, const float* W1, u16t* xb, u16t* WT, float* Beff)
{
    __shared__ __align__(16) char sm[32768];
    ph_prep(blockIdx.x, threadIdx.x, sm, x, Wq, Wk, Wv, Wo, W1, xb, WT, Beff);
}
__global__ __launch_bounds__(256) void kw_qkvac(
    const u16t* xb, const u16t* WT, const float* x, const float* Beff,
    const float* b1, u16t* qb, u16t* kb, u16t* vT, float* a, float* cc)
{
    __shared__ __align__(16) char sm[32768];
    ph_qkvac(blockIdx.x, threadIdx.x, sm, xb, WT, x, Beff, b1, qb, kb, vT, a, cc);
}
__global__ __launch_bounds__(256) void kw_scores(
    const u16t* qb, const u16t* kb, const float* a, const float* cc,
    const float* W2, const float* b2, u16t* P, float* lpart)
{
    __shared__ __align__(16) char sm[32768];
    ph_scores(blockIdx.x, threadIdx.x, sm, qb, kb, a, cc, W2, b2, P, lpart);
}
__global__ __launch_bounds__(256) void kw_pv(
    const u16t* P, const u16t* vT, const float* lpart, u16t* ao)
{
    __shared__ __align__(16) char sm[32768];
    ph_pv(blockIdx.x, threadIdx.x, sm, P, vT, lpart, ao);
}
__global__ __launch_bounds__(256) void kw_out(
    const u16t* ao, const u16t* WT, const float* bo, float* out)
{
    __shared__ __align__(16) char sm[32768];
    ph_out(blockIdx.x, threadIdx.x, sm, ao, WT, bo, out);
}

// ---------------------------------------------------------------------- host
extern "C" void kernel_launch(void* const* d_in, const int* in_sizes, int n_in,
                              void* d_out, int out_size, void* d_ws, size_t ws_size,
                              hipStream_t stream)
{
    const float* x  = (const float*)d_in[0];
    const float* Wq = (const float*)d_in[1];
    const float* Wk = (const float*)d_in[2];
    const float* Wv = (const float*)d_in[3];
    const float* Wo = (const float*)d_in[4];
    const float* bo = (const float*)d_in[5];
    const float* W1 = (const float*)d_in[6];
    const float* b1 = (const float*)d_in[7];
    const float* W2 = (const float*)d_in[8];
    const float* b2 = (const float*)d_in[9];
    float* out = (float*)d_out;

    char* ws = (char*)d_ws;
    size_t off = 0;
    auto carve = [&](size_t bytes) { void* p = ws + off; off += (bytes + 255) & ~(size_t)255; return p; };
    u16t* xb   = (u16t*)carve((size_t)2048 * 512 * 2);
    u16t* WT   = (u16t*)carve((size_t)4 * 512 * 512 * 2);
    u16t* qb   = (u16t*)carve((size_t)2048 * 512 * 2);
    u16t* kb   = (u16t*)carve((size_t)2048 * 512 * 2);
    u16t* vT   = (u16t*)carve((size_t)2 * 512 * 1024 * 2);
    float* Beff = (float*)carve((size_t)512 * 256 * 4);
    float* a   = (float*)carve((size_t)2048 * 128 * 4);
    float* c   = (float*)carve((size_t)2048 * 128 * 4);
    u16t* P    = (u16t*)carve((size_t)4 * 1024 * 1024 * 2);
    float* lpart = (float*)carve((size_t)16 * 4 * 1024 * 4);
    u16t* ao   = (u16t*)carve((size_t)2048 * 512 * 2);
    (void)ws_size;

    // cooperative feasibility (deterministic per process)
    int nb = 0;
    hipError_t qerr = hipOccupancyMaxActiveBlocksPerMultiprocessor(
        &nb, (const void*)k_mega, 256, 0);
    int numCU = 0;
    {
        hipDeviceProp_t prop;
        int dev = 0;
        if (hipGetDevice(&dev) == hipSuccess &&
            hipGetDeviceProperties(&prop, dev) == hipSuccess)
            numCU = prop.multiProcessorCount;
    }
    bool coop_ok = (qerr == hipSuccess) && (nb >= 1) && (numCU > 0) &&
                   ((long)nb * numCU >= 512);
    if (coop_ok) {
        void* args[] = {
            (void*)&x, (void*)&Wq, (void*)&Wk, (void*)&Wv, (void*)&Wo,
            (void*)&bo, (void*)&W1, (void*)&b1, (void*)&W2, (void*)&b2,
            (void*)&xb, (void*)&WT, (void*)&Beff, (void*)&qb, (void*)&kb,
            (void*)&vT, (void*)&a, (void*)&c, (void*)&P, (void*)&lpart,
            (void*)&ao, (void*)&out
        };
        hipError_t lerr = hipLaunchCooperativeKernel(
            (const void*)k_mega, dim3(512), dim3(256), args, 0, stream);
        if (lerr == hipSuccess) return;
        (void)hipGetLastError();   // clear; fall through to separate launches
    }
    kw_prep<<<dim3(2560), dim3(256), 0, stream>>>(x, Wq, Wk, Wv, Wo, W1, xb, WT, Beff);
    kw_qkvac<<<dim3(1024), dim3(256), 0, stream>>>(xb, WT, x, Beff, b1, qb, kb, vT, a, c);
    kw_scores<<<dim3(1024), dim3(256), 0, stream>>>(qb, kb, a, c, W2, b2, P, lpart);
    kw_pv<<<dim3(512), dim3(256), 0, stream>>>(P, vT, lpart, ao);
    kw_out<<<dim3(512), dim3(256), 0, stream>>>(ao, WT, bo, out);
}

// Round 19
// 99.663 us; speedup vs baseline: 1.4882x; 1.4882x over previous
//
#include <hip/hip_runtime.h>

// AdaptiveSparsityAttention on MI355X (gfx950).
// f32 in/out, internal bf16 MFMA; mask logits in pure f32 via algebraic
// fusion:  a = x @ (0.5*(Wq[:,:256]+Wq[:,256:]) @ W1[:256]) + b1.
//
// R19 = exact resubmission of R16 (best measured: 99.9us).
//   R17/R18 (persistent cooperative kernel) both failed: launch rejection
//   (48KB LDS > coop co-residency budget), then scratch-traffic pathology
//   in the shared-phase-body fallback (70MB fetch/122MB write on qkvac).
//   Locking in the 5-launch composition: prep, qkvac, scores(BM=32), pv, out.

typedef unsigned short u16t;
typedef __bf16 bf16x8 __attribute__((ext_vector_type(8)));
typedef float f32x4 __attribute__((ext_vector_type(4)));

#define B_SZ 2
#define S_SZ 1024
#define D_SZ 512
#define DH 256
#define HH 128   // hidden dim of sparsity predictor

static __device__ __forceinline__ u16t f2b(float f) {
    unsigned int u = __builtin_bit_cast(unsigned int, f);
    u += 0x7FFFu + ((u >> 16) & 1u);
    return (u16t)(u >> 16);
}

static __device__ __forceinline__ f32x4 mfma16(bf16x8 a, bf16x8 b, f32x4 c) {
    return __builtin_amdgcn_mfma_f32_16x16x32_bf16(a, b, c, 0, 0, 0);
}

static __device__ __forceinline__ void gload16(const void* g, void* l) {
    __builtin_amdgcn_global_load_lds(
        (const __attribute__((address_space(1))) void*)g,
        (__attribute__((address_space(3))) void*)l, 16, 0, 0);
}

// ---------------------------------------------------------- K0: fused prep
// blocks [0,1024): x->bf16 | [1024,2048): W transposes | [2048,2560): Beff
__global__ __launch_bounds__(256) void k_prep(
    const float* __restrict__ x,
    const float* __restrict__ Wq, const float* __restrict__ Wk,
    const float* __restrict__ Wv, const float* __restrict__ Wo,
    const float* __restrict__ W1,
    u16t* __restrict__ xb, u16t* __restrict__ WT, float* __restrict__ Beff)
{
    __shared__ float smf[1088];   // union: tile[32][33] (trans) | wm[2][256] (eff)
    int bidx = blockIdx.x;
    int t = threadIdx.x;
    if (bidx < 1024) {
        int idx = (bidx * 256 + t) * 4;
        float4 v = *(const float4*)(x + idx);
        u16t* o = xb + idx;
        o[0] = f2b(v.x); o[1] = f2b(v.y); o[2] = f2b(v.z); o[3] = f2b(v.w);
    } else if (bidx < 2048) {
        int t2 = bidx - 1024;
        int z = t2 >> 8, rem = t2 & 255;
        int n0 = (rem & 15) * 32, k0 = (rem >> 4) * 32;
        const float* W = z == 0 ? Wq : z == 1 ? Wk : z == 2 ? Wv : Wo;
        u16t* WTz = WT + (size_t)z * D_SZ * D_SZ;
        float (*tile)[33] = (float(*)[33])smf;
        int r = t >> 3, c4 = (t & 7) * 4;
        float4 v = *(const float4*)(W + (size_t)(k0 + r) * D_SZ + n0 + c4);
        tile[r][c4] = v.x; tile[r][c4 + 1] = v.y; tile[r][c4 + 2] = v.z; tile[r][c4 + 3] = v.w;
        __syncthreads();
        u16t o[4];
        o[0] = f2b(tile[c4][r]); o[1] = f2b(tile[c4 + 1][r]);
        o[2] = f2b(tile[c4 + 2][r]); o[3] = f2b(tile[c4 + 3][r]);
        *(ushort4*)(WTz + (size_t)(n0 + r) * D_SZ + k0 + c4) = *(ushort4*)o;
    } else {
        int k = bidx - 2048;   // 0..511
        float* wm0 = smf;
        float* wm1 = smf + 256;
        const float* wrq = Wq + (size_t)k * D_SZ;
        const float* wrk = Wk + (size_t)k * D_SZ;
        wm0[t & 255] = 0.5f * (wrq[t & 255] + wrq[(t & 255) + DH]);
        wm1[t & 255] = 0.5f * (wrk[t & 255] + wrk[(t & 255) + DH]);
        __syncthreads();
        int half = t >> 7, hcol = t & 127;
        const float* wm = half ? wm1 : wm0;
        const float* W1h = W1 + (half ? (size_t)DH * HH : 0);
        float s = 0.f;
        for (int d = 0; d < 256; ++d) s += wm[d] * W1h[(size_t)d * HH + hcol];
        Beff[(size_t)k * 256 + half * 128 + hcol] = s;
    }
}

// ---------------------------- 2-phase double-buffered GEMM mainloop (swizzled)
// C[BM=MF*64][BN=NF*16] per block (256 thr, 4 waves; wave w owns MF*16 rows).
// LDS physical slot p of row r holds logical 16B-slot p^(r&7): staged by
// swizzling the GLOBAL source column; frag reads use slot (kk*4+kg)^(r&7).
template<int MF, int NF>
static __device__ __forceinline__ void gemm_db(
    const u16t* __restrict__ A, int lda, const u16t* __restrict__ B, int ldb,
    int K, int tid, u16t* Als, u16t* Bls, f32x4 acc[MF][NF])
{
    const int w = tid >> 6, lane = tid & 63;
    const int lr = lane & 15, kg = lane >> 4;
    const int srow = lane >> 3;
    const int scol = ((lane & 7) ^ srow) * 8;   // swizzled global col (u16)
    const int ABUF = MF * 4096;   // u16 elems per A buffer
    const int BBUF = NF * 1024;   // u16 elems per B buffer
    auto stage = [&](int bb, int k0) {
#pragma unroll
        for (int q = 0; q < MF * 2; ++q) {
            int ci = w * (MF * 2) + q;
            gload16(A + (size_t)(ci * 8 + srow) * lda + k0 + scol,
                    Als + bb * ABUF + ci * 512);
        }
#pragma unroll
        for (int q = 0; q < NF / 2; ++q) {
            int cj = w * (NF / 2) + q;
            gload16(B + (size_t)(cj * 8 + srow) * ldb + k0 + scol,
                    Bls + bb * BBUF + cj * 512);
        }
    };
    stage(0, 0);
    __syncthreads();
    const int nt = K / 64;
    for (int t = 0; t < nt; ++t) {
        int cur = t & 1;
        if (t + 1 < nt) stage(cur ^ 1, (t + 1) * 64);
        const u16t* Ab = Als + cur * ABUF;
        const u16t* Bb = Bls + cur * BBUF;
#pragma unroll
        for (int kk = 0; kk < 2; ++kk) {
            bf16x8 af[MF], bfr[NF];
#pragma unroll
            for (int fi = 0; fi < MF; ++fi) {
                int r = w * (MF * 16) + fi * 16 + lr;
                af[fi] = *(const bf16x8*)(&Ab[r * 64 + (((kk * 4 + kg) ^ (r & 7)) << 3)]);
            }
#pragma unroll
            for (int fj = 0; fj < NF; ++fj) {
                int r = fj * 16 + lr;
                bfr[fj] = *(const bf16x8*)(&Bb[r * 64 + (((kk * 4 + kg) ^ (r & 7)) << 3)]);
            }
#pragma unroll
            for (int fi = 0; fi < MF; ++fi)
#pragma unroll
                for (int fj = 0; fj < NF; ++fj)
                    acc[fi][fj] = mfma16(af[fi], bfr[fj], acc[fi][fj]);
        }
        __syncthreads();
    }
}

// C-frag (fi,fj,rr): row = m0+w*MF*16+fi*16+kg*4+rr, col = n0+fj*16+lr  [m89]

// ------------------------------------------- K1: fused QKV GEMMs + mask-ac GEMM
// 1D grid, 640 blocks: [0,384) -> qkv (z = bid/128, MF=2); [384,640) -> ac.
__global__ __launch_bounds__(256) void k_qkvac(
    const u16t* __restrict__ xb, const u16t* __restrict__ WT,
    const float* __restrict__ x, const float* __restrict__ Beff,
    const float* __restrict__ b1,
    u16t* __restrict__ qb, u16t* __restrict__ kb, u16t* __restrict__ vT,
    float* __restrict__ a, float* __restrict__ cc)
{
    __shared__ __align__(16) char sm[49152];   // qkv: A 2x16KB + B 2x8KB = 48KB
    int bid = blockIdx.x;
    int t = threadIdx.x;
    if (bid < 384) {
        u16t* Als = (u16t*)sm;
        u16t* Bls = (u16t*)(sm + 32768);
        int z = bid / 128, rem = bid & 127;
        int m0 = (rem >> 3) * 128, n0 = (rem & 7) * 64;
        const u16t* A = xb + (size_t)m0 * D_SZ;
        const u16t* Bt = WT + (size_t)z * D_SZ * D_SZ + (size_t)n0 * D_SZ;
        f32x4 acc[2][4] = {};
        gemm_db<2, 4>(A, D_SZ, Bt, D_SZ, D_SZ, t, Als, Bls, acc);
        int w = t >> 6, lane = t & 63, lr = lane & 15, kg = lane >> 4;
        if (z < 2) {
            u16t (*vls)[68] = (u16t(*)[68])sm;
            float scale = z == 0 ? 0.0625f : 1.0f;
#pragma unroll
            for (int fi = 0; fi < 2; ++fi)
#pragma unroll
                for (int fj = 0; fj < 4; ++fj)
#pragma unroll
                    for (int rr = 0; rr < 4; ++rr)
                        vls[w * 32 + fi * 16 + kg * 4 + rr][fj * 16 + lr]
                            = f2b(acc[fi][fj][rr] * scale);
            __syncthreads();
            u16t* dst = z == 0 ? qb : kb;
            int c8 = (t & 7) * 8, r0 = t >> 3;
#pragma unroll
            for (int p = 0; p < 4; ++p) {
                int r = r0 + p * 32;
                *(uint4*)(dst + (size_t)(m0 + r) * D_SZ + n0 + c8) = *(const uint4*)(&vls[r][c8]);
            }
        } else {
            u16t (*vls)[136] = (u16t(*)[136])sm;   // 64*136*2 = 17408
#pragma unroll
            for (int fi = 0; fi < 2; ++fi)
#pragma unroll
                for (int fj = 0; fj < 4; ++fj)
#pragma unroll
                    for (int rr = 0; rr < 4; ++rr)
                        vls[fj * 16 + lr][w * 32 + fi * 16 + kg * 4 + rr] = f2b(acc[fi][fj][rr]);
            __syncthreads();
            int b = m0 >> 10, s0 = m0 & 1023;
            int cr = t >> 2, seg = t & 3;
            const u16t* srcp = &vls[cr][seg * 32];
            u16t* dstp = vT + (((size_t)(b * D_SZ + n0 + cr)) << 10) + s0 + seg * 32;
#pragma unroll
            for (int qq = 0; qq < 4; ++qq)
                *(uint4*)(dstp + qq * 8) = *(const uint4*)(srcp + qq * 8);
        }
    } else {
        // [a|c] = x @ Beff (f32), a gets +b1. 64 rows x 32 cols, 4x2/thread.
        float (*xs)[68] = (float(*)[68])sm;            // 64x68
        float (*bsT)[68] = (float(*)[68])(sm + 17408); // 32x68 [n][k]
        int t2 = bid - 384;
        int r0 = (t2 & 31) * 64, n0 = (t2 >> 5) * 32;
        int ti = t >> 4, tj = t & 15;
        float acc[4][2] = {};
        for (int k0 = 0; k0 < 512; k0 += 64) {
            if (k0) __syncthreads();
#pragma unroll
            for (int p = 0; p < 4; ++p) {
                int idx = t + p * 256;
                int r = idx >> 4, c4 = (idx & 15) * 4;
                *(float4*)&xs[r][c4] = *(const float4*)(x + (size_t)(r0 + r) * D_SZ + k0 + c4);
            }
#pragma unroll
            for (int p = 0; p < 2; ++p) {
                int idx = t + p * 256;
                int k = idx >> 3, n4 = (idx & 7) * 4;
                float4 v = *(const float4*)(Beff + (size_t)(k0 + k) * 256 + n0 + n4);
                bsT[n4][k] = v.x; bsT[n4 + 1][k] = v.y; bsT[n4 + 2][k] = v.z; bsT[n4 + 3][k] = v.w;
            }
            __syncthreads();
#pragma unroll
            for (int kk = 0; kk < 16; ++kk) {
                float4 xv[4], bv[2];
#pragma unroll
                for (int ri = 0; ri < 4; ++ri) xv[ri] = *(const float4*)&xs[ti + 16 * ri][kk * 4];
#pragma unroll
                for (int rj = 0; rj < 2; ++rj) bv[rj] = *(const float4*)&bsT[tj + 16 * rj][kk * 4];
#pragma unroll
                for (int ri = 0; ri < 4; ++ri)
#pragma unroll
                    for (int rj = 0; rj < 2; ++rj)
                        acc[ri][rj] += xv[ri].x * bv[rj].x + xv[ri].y * bv[rj].y
                                     + xv[ri].z * bv[rj].z + xv[ri].w * bv[rj].w;
            }
        }
        bool isA = n0 < 128;
#pragma unroll
        for (int rj = 0; rj < 2; ++rj) {
            int col = n0 + tj + 16 * rj;
            float badd = isA ? b1[col] : 0.f;
#pragma unroll
            for (int ri = 0; ri < 4; ++ri) {
                int row = r0 + ti + 16 * ri;
                if (isA) a[(size_t)row * HH + col] = acc[ri][rj] + badd;
                else     cc[(size_t)row * HH + (col - 128)] = acc[ri][rj];
            }
        }
    }
}

// -------------- K2: fused mask + both-head scores, BM=32
// grid (16 jb, 32 mt, 2 b) = 1024 blocks. Phase 1: 32x64 mask tile (two
// jh-halves, at/ct[32][132] in LDS). Phase 2: QK^T h0+h1 (K=512 concat,
// swizzled db LDS; waves partition j). Phase 3: exp+mask -> P + lpart
// (cross-wave lsum reduce, fixed order). LDS 36KB.
__global__ __launch_bounds__(256) void k_scores(
    const u16t* __restrict__ qb, const u16t* __restrict__ kb,
    const float* __restrict__ a, const float* __restrict__ c,
    const float* __restrict__ W2, const float* __restrict__ b2,
    u16t* __restrict__ P, float* __restrict__ lpart)
{
    __shared__ __align__(16) char sm[36864];
    float (*at)[132] = (float(*)[132])sm;                       // 16896B
    float (*ct)[132] = (float(*)[132])(sm + 16896);             // 16896B
    unsigned char (*msk)[64] = (unsigned char(*)[64])(sm + 33792);  // 2048B persists
    float* w2s  = (float*)(sm + 35840);                         // 512B persists
    float* lsum = (float*)(sm + 36352);                         // 4x32 f32 = 512B
    int b = blockIdx.z, mt = blockIdx.y, jb = blockIdx.x;
    int m0 = mt * 32, j0 = jb * 64;
    int t = threadIdx.x;
    if (t < 128) w2s[t] = W2[t];
    float fb2 = b2[0];
    int ti = t >> 4, tj = t & 15;
    // load a-tile (32 rows)
#pragma unroll
    for (int p = 0; p < 4; ++p) {
        int idx = t + p * 256;
        int r = idx >> 5, c4 = (idx & 31) * 4;
        *(float4*)&at[r][c4] = *(const float4*)(a + ((size_t)(b * S_SZ + m0 + r)) * HH + c4);
    }
    // ---- phase 1: mask tile (two j-halves of 32) ----
#pragma unroll
    for (int jh = 0; jh < 2; ++jh) {
        __syncthreads();   // jh=0: at/w2s visible; jh=1: prev ct readers done
#pragma unroll
        for (int p = 0; p < 4; ++p) {
            int idx = t + p * 256;
            int r = idx >> 5, c4 = (idx & 31) * 4;
            *(float4*)&ct[r][c4] =
                *(const float4*)(c + ((size_t)(b * S_SZ + j0 + jh * 32 + r)) * HH + c4);
        }
        __syncthreads();
        float accm[2][2];
#pragma unroll
        for (int ri = 0; ri < 2; ++ri)
#pragma unroll
            for (int rj = 0; rj < 2; ++rj) accm[ri][rj] = fb2;
#pragma unroll 2
        for (int h4 = 0; h4 < 32; ++h4) {
            float4 wv = ((const float4*)w2s)[h4];
            float4 av[2], cv[2];
#pragma unroll
            for (int ri = 0; ri < 2; ++ri) av[ri] = *(const float4*)&at[ti + 16 * ri][h4 * 4];
#pragma unroll
            for (int rj = 0; rj < 2; ++rj) cv[rj] = *(const float4*)&ct[tj + 16 * rj][h4 * 4];
#pragma unroll
            for (int ri = 0; ri < 2; ++ri)
#pragma unroll
                for (int rj = 0; rj < 2; ++rj) {
                    accm[ri][rj] += fmaxf(av[ri].x + cv[rj].x, 0.f) * wv.x;
                    accm[ri][rj] += fmaxf(av[ri].y + cv[rj].y, 0.f) * wv.y;
                    accm[ri][rj] += fmaxf(av[ri].z + cv[rj].z, 0.f) * wv.z;
                    accm[ri][rj] += fmaxf(av[ri].w + cv[rj].w, 0.f) * wv.w;
                }
        }
#pragma unroll
        for (int ri = 0; ri < 2; ++ri)
#pragma unroll
            for (int rj = 0; rj < 2; ++rj)
                msk[ti + 16 * ri][jh * 32 + tj + 16 * rj] = accm[ri][rj] > 0.f ? 1 : 0;
    }
    __syncthreads();   // at/ct readers done; GEMM bufs overlay at/ct space
    // ---- phase 2: QK^T both heads (K=512 concat; qb pre-scaled by 1/16) ----
    // Waves partition j: wave w owns j-frag w (cols w*16..+16), all of M=32.
    u16t* Als = (u16t*)sm;             // 2 x 4KB
    u16t* Bls = (u16t*)(sm + 8192);    // 2 x 8KB
    const u16t* A = qb + (size_t)(b * S_SZ + m0) * D_SZ;
    const u16t* B = kb + (size_t)(b * S_SZ + j0) * D_SZ;
    const int w = t >> 6, lane = t & 63, lr = lane & 15, kg = lane >> 4;
    const int srow = lane >> 3;
    const int scol = ((lane & 7) ^ srow) * 8;   // swizzled global col (u16)
    auto stage = [&](int bb, int k0) {
        gload16(A + (size_t)(w * 8 + srow) * D_SZ + k0 + scol, Als + bb * 2048 + w * 512);
#pragma unroll
        for (int q = 0; q < 2; ++q) {
            int cj = w * 2 + q;
            gload16(B + (size_t)(cj * 8 + srow) * D_SZ + k0 + scol, Bls + bb * 4096 + cj * 512);
        }
    };
    f32x4 acc0[2] = {}, acc1[2] = {};
    stage(0, 0);
    __syncthreads();
#pragma unroll
    for (int t8 = 0; t8 < 8; ++t8) {
        int cur = t8 & 1;
        if (t8 < 7) stage(cur ^ 1, (t8 + 1) * 64);
        const u16t* Ab = Als + cur * 2048;
        const u16t* Bb = Bls + cur * 4096;
#pragma unroll
        for (int kk = 0; kk < 2; ++kk) {
            int rb = w * 16 + lr;
            bf16x8 bfr = *(const bf16x8*)(&Bb[rb * 64 + (((kk * 4 + kg) ^ (rb & 7)) << 3)]);
            bf16x8 af[2];
#pragma unroll
            for (int fi = 0; fi < 2; ++fi) {
                int ra = fi * 16 + lr;
                af[fi] = *(const bf16x8*)(&Ab[ra * 64 + (((kk * 4 + kg) ^ (ra & 7)) << 3)]);
            }
            if (t8 < 4) {
#pragma unroll
                for (int fi = 0; fi < 2; ++fi) acc0[fi] = mfma16(af[fi], bfr, acc0[fi]);
            } else {
#pragma unroll
                for (int fi = 0; fi < 2; ++fi) acc1[fi] = mfma16(af[fi], bfr, acc1[fi]);
            }
        }
        __syncthreads();
    }
    // ---- phase 3: exp + mask + lpart + P store, per head ----
    // thread value (h, fi, rr): i_local = fi*16+kg*4+rr, j_local = w*16+lr
    u16t (*vls)[68] = (u16t(*)[68])sm;   // 32x68 u16 = 4352B, overlays GEMM bufs
#pragma unroll
    for (int h = 0; h < 2; ++h) {
#pragma unroll
        for (int fi = 0; fi < 2; ++fi)
#pragma unroll
            for (int rr = 0; rr < 4; ++rr) {
                int il = fi * 16 + kg * 4 + rr;
                int jl = w * 16 + lr;
                float s = h ? acc1[fi][rr] : acc0[fi][rr];
                float e = msk[il][jl] ? __expf(s) : 0.f;
                if (h) acc1[fi][rr] = e; else acc0[fi][rr] = e;
            }
        // per-wave partial row sums -> lsum[w][il]
#pragma unroll
        for (int fi = 0; fi < 2; ++fi)
#pragma unroll
            for (int rr = 0; rr < 4; ++rr) {
                float rs = h ? acc1[fi][rr] : acc0[fi][rr];
                rs += __shfl_xor(rs, 1); rs += __shfl_xor(rs, 2);
                rs += __shfl_xor(rs, 4); rs += __shfl_xor(rs, 8);
                if (lr == 0) lsum[w * 32 + fi * 16 + kg * 4 + rr] = rs;
            }
        __syncthreads();
        if (t < 32) {   // fixed-order cross-wave sum (deterministic)
            float l = lsum[t] + lsum[32 + t] + lsum[64 + t] + lsum[96 + t];
            lpart[((size_t)(jb * 4 + b * 2 + h) << 10) + m0 + t] = l;
        }
        // stage P tile + coalesced store
#pragma unroll
        for (int fi = 0; fi < 2; ++fi)
#pragma unroll
            for (int rr = 0; rr < 4; ++rr)
                vls[fi * 16 + kg * 4 + rr][w * 16 + lr]
                    = f2b(h ? acc1[fi][rr] : acc0[fi][rr]);
        __syncthreads();
        int r = t >> 3, c8 = (t & 7) * 8;
        *(uint4*)(P + ((size_t)(b * 2 + h) << 20) + ((size_t)(m0 + r) << 10) + j0 + c8)
            = *(const uint4*)(&vls[r][c8]);
        __syncthreads();
    }
}

// ----------------------------- K3: PV (+ diag(1/l) epilogue), BM=64
// grid (8,16,4): n0=x*32, m0=y*64.
__global__ __launch_bounds__(256) void k_pv(
    const u16t* __restrict__ P, const u16t* __restrict__ vT,
    const float* __restrict__ lpart, u16t* __restrict__ ao)
{
    __shared__ __align__(16) u16t sm[12288];   // A 2x8KB + B 2x4KB = 24KB
    __shared__ float invl[64];
    u16t* Als = sm;
    u16t* Bls = sm + 8192;
    int bh = blockIdx.z, b = bh >> 1, h = bh & 1;
    int m0 = blockIdx.y * 64, n0 = blockIdx.x * 32;
    int t = threadIdx.x;
    if (t < 64) {   // fixed-order row-sum over 16 j-block partials (deterministic)
        float l = 0.f;
        for (int jb = 0; jb < 16; ++jb)
            l += lpart[((size_t)(jb * 4 + bh) << 10) + m0 + t];
        invl[t] = l > 0.f ? 1.0f / l : 0.f;
    }
    const u16t* A = P + ((size_t)bh << 20) + (size_t)m0 * S_SZ;
    const u16t* Bt = vT + ((size_t)(b * D_SZ + h * DH + n0)) * S_SZ;
    f32x4 acc[1][2] = {};
    gemm_db<1, 2>(A, S_SZ, Bt, S_SZ, S_SZ, t, Als, Bls, acc);
    int w = t >> 6, lane = t & 63, lr = lane & 15, kg = lane >> 4;
    u16t (*ols)[40] = (u16t(*)[40])sm;   // 64x40 u16 = 5120B
#pragma unroll
    for (int fj = 0; fj < 2; ++fj)
#pragma unroll
        for (int rr = 0; rr < 4; ++rr) {
            int rl = w * 16 + kg * 4 + rr;
            ols[rl][fj * 16 + lr] = f2b(acc[0][fj][rr] * invl[rl]);
        }
    __syncthreads();
    int r = t >> 2, c8 = (t & 3) * 8;
    *(uint4*)(ao + ((size_t)(b * S_SZ + m0 + r)) * D_SZ + h * DH + n0 + c8)
        = *(const uint4*)(&ols[r][c8]);
}

// ------------------------------------------ K4: out = ao@Wo+bo, BM=64
// grid (16,32): n0=x*32, m0=y*64.
__global__ __launch_bounds__(256) void k_out(
    const u16t* __restrict__ ao, const u16t* __restrict__ WoT,
    const float* __restrict__ bo, float* __restrict__ out)
{
    __shared__ __align__(16) u16t sm[12288];   // A 2x8KB + B 2x4KB = 24KB
    u16t* Als = sm;
    u16t* Bls = sm + 8192;
    int m0 = blockIdx.y * 64, n0 = blockIdx.x * 32;
    const u16t* A = ao + (size_t)m0 * D_SZ;
    const u16t* Bt = WoT + (size_t)n0 * D_SZ;
    f32x4 acc[1][2] = {};
    gemm_db<1, 2>(A, D_SZ, Bt, D_SZ, D_SZ, threadIdx.x, Als, Bls, acc);
    int w = threadIdx.x >> 6, lane = threadIdx.x & 63, lr = lane & 15, kg = lane >> 4;
    float (*ols)[36] = (float(*)[36])sm;   // 64x36 f32 = 9216B
#pragma unroll
    for (int fj = 0; fj < 2; ++fj)
#pragma unroll
        for (int rr = 0; rr < 4; ++rr) {
            int rl = w * 16 + kg * 4 + rr;
            ols[rl][fj * 16 + lr] = acc[0][fj][rr] + bo[n0 + fj * 16 + lr];
        }
    __syncthreads();
    int r0 = threadIdx.x >> 3, c4 = (threadIdx.x & 7) * 4;
#pragma unroll
    for (int p = 0; p < 2; ++p) {
        int r = r0 + p * 32;
        *(float4*)(out + (size_t)(m0 + r) * D_SZ + n0 + c4) = *(const float4*)(&ols[r][c4]);
    }
}

// ---------------------------------------------------------------------- host
extern "C" void kernel_launch(void* const* d_in, const int* in_sizes, int n_in,
                              void* d_out, int out_size, void* d_ws, size_t ws_size,
                              hipStream_t stream)
{
    const float* x  = (const float*)d_in[0];
    const float* Wq = (const float*)d_in[1];
    const float* Wk = (const float*)d_in[2];
    const float* Wv = (const float*)d_in[3];
    const float* Wo = (const float*)d_in[4];
    const float* bo = (const float*)d_in[5];
    const float* W1 = (const float*)d_in[6];
    const float* b1 = (const float*)d_in[7];
    const float* W2 = (const float*)d_in[8];
    const float* b2 = (const float*)d_in[9];
    float* out = (float*)d_out;

    // workspace carve (all 256B-aligned)
    char* ws = (char*)d_ws;
    size_t off = 0;
    auto carve = [&](size_t bytes) { void* p = ws + off; off += (bytes + 255) & ~(size_t)255; return p; };
    u16t* xb   = (u16t*)carve((size_t)2048 * 512 * 2);
    u16t* WT   = (u16t*)carve((size_t)4 * 512 * 512 * 2);
    u16t* qb   = (u16t*)carve((size_t)2048 * 512 * 2);
    u16t* kb   = (u16t*)carve((size_t)2048 * 512 * 2);
    u16t* vT   = (u16t*)carve((size_t)2 * 512 * 1024 * 2);
    float* Beff = (float*)carve((size_t)512 * 256 * 4);
    float* a   = (float*)carve((size_t)2048 * 128 * 4);
    float* c   = (float*)carve((size_t)2048 * 128 * 4);
    u16t* P    = (u16t*)carve((size_t)4 * 1024 * 1024 * 2);
    float* lpart = (float*)carve((size_t)16 * 4 * 1024 * 4);
    u16t* ao   = (u16t*)carve((size_t)2048 * 512 * 2);
    (void)ws_size;

    k_prep<<<dim3(2560), dim3(256), 0, stream>>>(x, Wq, Wk, Wv, Wo, W1, xb, WT, Beff);
    k_qkvac<<<dim3(640), dim3(256), 0, stream>>>(xb, WT, x, Beff, b1, qb, kb, vT, a, c);
    k_scores<<<dim3(16, 32, 2), dim3(256), 0, stream>>>(qb, kb, a, c, W2, b2, P, lpart);
    k_pv<<<dim3(8, 16, 4), dim3(256), 0, stream>>>(P, vT, lpart, ao);
    k_out<<<dim3(16, 32), dim3(256), 0, stream>>>(ao, WT + (size_t)3 * 512 * 512, bo, out);
}